// Round 4
// baseline (429.770 us; speedup 1.0000x reference)
//
#include <hip/hip_runtime.h>
#include <hip/hip_fp16.h>

// Winograd F(4x4,3x3), fp32 in/out. x:[16,64,130,130] w:[64,64,3,3] -> y:[16,64,128,128]
// Pipeline: k_filter (U fp16 hi/lo) -> k_input (V fp16 hi/lo, [ab][p][c] packed) ->
//           k_gemm (3-product f16 MFMA, M fp32 [ab][k][p]) -> k_out2 (A^T M A).
// half2 packing: each uint32 = (hi in bits 0..15, lo in bits 16..31) for one c.
// V row per (ab,p): 64 uints = 256 B, 16B-aligned -> coalesced stores + clean LDS staging.

typedef _Float16 half8_t __attribute__((ext_vector_type(8)));
typedef float floatx16 __attribute__((ext_vector_type(16)));

__constant__ float c_AT[24] = {   // c_AT[i*4+u] = A_T[u][i]
  1.f, 0.f, 0.f, 0.f,
  1.f, 1.f, 1.f, 1.f,
  1.f,-1.f, 1.f,-1.f,
  1.f, 2.f, 4.f, 8.f,
  1.f,-2.f, 4.f,-8.f,
  0.f, 0.f, 0.f, 1.f
};

__device__ __forceinline__ uint32_t pack_hilo(float v) {
  __half hh = __float2half(v);
  float r = v - __half2float(hh);
  __half hl = __float2half(r);
  return (uint32_t)__half_as_ushort(hh) | ((uint32_t)__half_as_ushort(hl) << 16);
}
// build hi-halfs word from two packed uints (c even, c odd)
__device__ __forceinline__ uint32_t phi(uint32_t w0, uint32_t w1) {
  return __builtin_amdgcn_perm(w1, w0, 0x05040100u);   // [w0.b0,w0.b1,w1.b0,w1.b1]
}
__device__ __forceinline__ uint32_t plo(uint32_t w0, uint32_t w1) {
  return __builtin_amdgcn_perm(w1, w0, 0x07060302u);   // [w0.b2,w0.b3,w1.b2,w1.b3]
}
union H8 { uint32_t u[4]; half8_t h; };

// ---------------- K0: filter transform U = G w G^T -> packed hi/lo, [ab][k][c] ----------------
__global__ __launch_bounds__(256) void k_filter(const float* __restrict__ w,
                                                uint32_t* __restrict__ U) {
  int g = blockIdx.x * 256 + threadIdx.x;     // 0..4095
  int c = g & 63;                              // lane-fast -> coalesced U stores
  int k = g >> 6;
  const float* wp = w + (size_t)(k * 64 + c) * 9;
  float w00 = wp[0], w01 = wp[1], w02 = wp[2];
  float w10 = wp[3], w11 = wp[4], w12 = wp[5];
  float w20 = wp[6], w21 = wp[7], w22 = wp[8];
  const float G[6][3] = {
    {0.25f, 0.f, 0.f},
    {-1.f/6.f, -1.f/6.f, -1.f/6.f},
    {-1.f/6.f,  1.f/6.f, -1.f/6.f},
    {1.f/24.f,  1.f/12.f, 1.f/6.f},
    {1.f/24.f, -1.f/12.f, 1.f/6.f},
    {0.f, 0.f, 1.f}
  };
  float t[6][3];
#pragma unroll
  for (int a = 0; a < 6; ++a) {
    t[a][0] = G[a][0]*w00 + G[a][1]*w10 + G[a][2]*w20;
    t[a][1] = G[a][0]*w01 + G[a][1]*w11 + G[a][2]*w21;
    t[a][2] = G[a][0]*w02 + G[a][1]*w12 + G[a][2]*w22;
  }
#pragma unroll
  for (int a = 0; a < 6; ++a) {
#pragma unroll
    for (int b = 0; b < 6; ++b) {
      float u = G[b][0]*t[a][0] + G[b][1]*t[a][1] + G[b][2]*t[a][2];
      U[((size_t)(a*6+b)*64 + k)*64 + c] = pack_hilo(u);
    }
  }
}

// ---------------- K1: input transform -> V[ab][p][c] packed hi/lo ----------------
// block = (n, ty2: 2 tile-rows = 64 p, cg: 16 c). 16 c-chunks of 4. grid = cn*64.
__global__ __launch_bounds__(256) void k_input(const float* __restrict__ x,
                                               uint32_t* __restrict__ V,
                                               int n0, int Pchunk) {
  __shared__ float XL[4*1330];          // [4c][10 rows x 133] (row pad -> 2-way max)
  __shared__ uint32_t VL[36*64*4];      // [ab][64p][4c] packed
  const int tid = threadIdx.x;
  const int bi  = blockIdx.x;
  const int cg  = bi & 3;
  const int ty2 = (bi >> 2) & 15;
  const int nl  = bi >> 6;
  const int h0  = ty2 * 8;              // x rows h0..h0+9

  const int c4 = tid & 3;               // compute mapping
  const int p  = tid >> 2;              // 0..63
  const int trow = p >> 5, pl = p & 31;

  for (int ch = 0; ch < 4; ++ch) {
    const int cbase = cg*16 + ch*4;
    __syncthreads();                    // protect XL/VL reuse from previous iter
    // stage x[4c][10r][130] (float2 global loads, scalar LDS writes)
    for (int idx = tid; idx < 4*10*65; idx += 256) {
      int cc = idx / 650; int rem = idx - cc*650; int r = rem/65; int j = rem - r*65;
      const float* xr = x + ((size_t)((n0+nl)*64 + cbase + cc)*130 + h0 + r)*130;
      float2 v = *(const float2*)(xr + j*2);
      XL[cc*1330 + r*133 + j*2]     = v.x;
      XL[cc*1330 + r*133 + j*2 + 1] = v.y;
    }
    __syncthreads();
    // transform one (p, c) per thread
    const float* bl = &XL[c4*1330 + (trow*4)*133 + pl*4];
    float t1[6][6];
#pragma unroll
    for (int j = 0; j < 6; ++j) {
      float d0 = bl[0*133+j], d1 = bl[1*133+j], d2 = bl[2*133+j];
      float d3 = bl[3*133+j], d4 = bl[4*133+j], d5 = bl[5*133+j];
      t1[0][j] =  4.f*d0 - 5.f*d2 + d4;
      t1[1][j] = -4.f*d1 - 4.f*d2 + d3 + d4;
      t1[2][j] =  4.f*d1 - 4.f*d2 - d3 + d4;
      t1[3][j] = -2.f*d1 -     d2 + 2.f*d3 + d4;
      t1[4][j] =  2.f*d1 -     d2 - 2.f*d3 + d4;
      t1[5][j] =  4.f*d1 - 5.f*d3 + d5;
    }
#pragma unroll
    for (int a = 0; a < 6; ++a) {
      float s0=t1[a][0], s1=t1[a][1], s2=t1[a][2], s3=t1[a][3], s4=t1[a][4], s5=t1[a][5];
      float v0 =  4.f*s0 - 5.f*s2 + s4;
      float v1 = -4.f*s1 - 4.f*s2 + s3 + s4;
      float v2 =  4.f*s1 - 4.f*s2 - s3 + s4;
      float v3 = -2.f*s1 -     s2 + 2.f*s3 + s4;
      float v4 =  2.f*s1 -     s2 - 2.f*s3 + s4;
      float v5 =  4.f*s1 - 5.f*s3 + s5;
      VL[(a*6+0)*256 + p*4 + c4] = pack_hilo(v0);
      VL[(a*6+1)*256 + p*4 + c4] = pack_hilo(v1);
      VL[(a*6+2)*256 + p*4 + c4] = pack_hilo(v2);
      VL[(a*6+3)*256 + p*4 + c4] = pack_hilo(v3);
      VL[(a*6+4)*256 + p*4 + c4] = pack_hilo(v4);
      VL[(a*6+5)*256 + p*4 + c4] = pack_hilo(v5);
    }
    __syncthreads();
    // flush: (ab, pp) per thread-iter; b128 LDS read (16B lane stride) + dwordx4 store
#pragma unroll
    for (int i = 0; i < 9; ++i) {
      int e = i*256 + tid; int ab = e >> 6; int pp = e & 63;
      uint4 q = *(const uint4*)&VL[ab*256 + pp*4];
      size_t pglob = (size_t)nl*1024 + ty2*64 + pp;
      *(uint4*)&V[((size_t)ab*Pchunk + pglob)*64 + cbase] = q;
    }
  }
}

// ---------------- K2: 3-product f16 MFMA GEMM: M[ab][k][p] = sum_c U*V ----------------
// block = one ab x 128 p x 64 k; Vs = [128p][16 units of 16B], unit xor-swizzled by p&15.
__global__ __launch_bounds__(256) void k_gemm(const uint32_t* __restrict__ V,
                                              const uint32_t* __restrict__ U,
                                              float* __restrict__ M,
                                              int Pchunk, int nPB) {
  __shared__ uint32_t Vs[128*64];       // 32 KB
  const int tid  = threadIdx.x;
  const int lane = tid & 63;
  const int wv   = tid >> 6;
  const unsigned bx = blockIdx.x;
  const int ab = bx / (unsigned)nPB;
  const int pb = bx - ab * nPB;
  const int p0 = pb * 128;

  // ---- stage V tile [128p][64c] (2048 uint4), swizzled units
  const uint4* Vg = (const uint4*)(V + ((size_t)ab*Pchunk + p0)*64);
  uint4 tmp[8];
#pragma unroll
  for (int i = 0; i < 8; ++i) tmp[i] = Vg[tid + i*256];
#pragma unroll
  for (int i = 0; i < 8; ++i) {
    int f = tid + i*256; int pp = f >> 4; int u = f & 15;
    *(uint4*)&Vs[pp*64 + (u ^ (pp & 15))*4] = tmp[i];
  }
  __syncthreads();

  // ---- preload U A-frags into regs: wave covers all 64 k (2 ktiles), lane m = k
  const int kg = lane >> 5;             // K-half of the MFMA
  const int m  = lane & 31;
  half8_t Uhi[2][4], Ulo[2][4];
#pragma unroll
  for (int t = 0; t < 2; ++t) {
    int k = t*32 + m;
    const uint32_t* ub = U + ((size_t)ab*64 + k)*64;
#pragma unroll
    for (int cc = 0; cc < 4; ++cc) {
      uint4 qa = *(const uint4*)(ub + cc*16 + kg*8);
      uint4 qb = *(const uint4*)(ub + cc*16 + kg*8 + 4);
      H8 hi, lo;
      hi.u[0] = phi(qa.x, qa.y); hi.u[1] = phi(qa.z, qa.w);
      hi.u[2] = phi(qb.x, qb.y); hi.u[3] = phi(qb.z, qb.w);
      lo.u[0] = plo(qa.x, qa.y); lo.u[1] = plo(qa.z, qa.w);
      lo.u[2] = plo(qb.x, qb.y); lo.u[3] = plo(qb.z, qb.w);
      Uhi[t][cc] = hi.h; Ulo[t][cc] = lo.h;
    }
  }

  floatx16 acc[2];
#pragma unroll
  for (int t = 0; t < 2; ++t)
#pragma unroll
    for (int r = 0; r < 16; ++r) acc[t][r] = 0.f;

  const int plane = wv*32 + m;          // this wave's p for B-frags
#pragma unroll
  for (int cc = 0; cc < 4; ++cc) {
    int u0 = (cc*4 + kg*2) ^ (plane & 15);
    int u1 = (cc*4 + kg*2 + 1) ^ (plane & 15);
    uint4 qa = *(const uint4*)&Vs[plane*64 + u0*4];
    uint4 qb = *(const uint4*)&Vs[plane*64 + u1*4];
    H8 vhi, vlo;
    vhi.u[0] = phi(qa.x, qa.y); vhi.u[1] = phi(qa.z, qa.w);
    vhi.u[2] = phi(qb.x, qb.y); vhi.u[3] = phi(qb.z, qb.w);
    vlo.u[0] = plo(qa.x, qa.y); vlo.u[1] = plo(qa.z, qa.w);
    vlo.u[2] = plo(qb.x, qb.y); vlo.u[3] = plo(qb.z, qb.w);
#pragma unroll
    for (int t = 0; t < 2; ++t) {
      acc[t] = __builtin_amdgcn_mfma_f32_32x32x16_f16(Uhi[t][cc], vhi.h, acc[t], 0, 0, 0);
      acc[t] = __builtin_amdgcn_mfma_f32_32x32x16_f16(Uhi[t][cc], vlo.h, acc[t], 0, 0, 0);
      acc[t] = __builtin_amdgcn_mfma_f32_32x32x16_f16(Ulo[t][cc], vhi.h, acc[t], 0, 0, 0);
    }
  }

  // ---- store M[ab][k][p]: C/D layout col(p)=lane&31, row(k)=(r&3)+8*(r>>2)+4*(lane>>5)
  const int pout = p0 + wv*32 + m;
#pragma unroll
  for (int t = 0; t < 2; ++t) {
#pragma unroll
    for (int r = 0; r < 16; ++r) {
      int k = t*32 + (r & 3) + 8*(r >> 2) + 4*kg;
      M[((size_t)ab*64 + k)*Pchunk + pout] = acc[t][r];
    }
  }
}

// ---------------- K3: output transform Y = A_T M A, 4 p per thread ----------------
__global__ __launch_bounds__(256) void k_out2(const float* __restrict__ M,
                                              float* __restrict__ out,
                                              int n0, int Pchunk, int bpk) {
  const unsigned bx = blockIdx.x;
  const int k    = bx / (unsigned)bpk;
  const int pblk = bx - k * bpk;
  const int p    = pblk * 1024 + threadIdx.x * 4;
  const int nl = p >> 10;
  const int ty = (p >> 5) & 31;
  const int tx = p & 31;

  const float* mp = M + (size_t)k * Pchunk + p;
  const size_t abstride = (size_t)64 * Pchunk;

  float Y[4][4][4];   // [u][v][pvec]
#pragma unroll
  for (int u = 0; u < 4; ++u)
#pragma unroll
    for (int v = 0; v < 4; ++v)
#pragma unroll
      for (int q = 0; q < 4; ++q) Y[u][v][q] = 0.f;

#pragma unroll
  for (int i = 0; i < 6; ++i) {
    float R[4][4];
#pragma unroll
    for (int v = 0; v < 4; ++v)
#pragma unroll
      for (int q = 0; q < 4; ++q) R[v][q] = 0.f;
#pragma unroll
    for (int j = 0; j < 6; ++j) {
      float4 m4 = *(const float4*)(mp + (size_t)(i * 6 + j) * abstride);
      float mm[4] = {m4.x, m4.y, m4.z, m4.w};
#pragma unroll
      for (int v = 0; v < 4; ++v) {
        float av = c_AT[j * 4 + v];
#pragma unroll
        for (int q = 0; q < 4; ++q) R[v][q] += av * mm[q];
      }
    }
#pragma unroll
    for (int u = 0; u < 4; ++u) {
      float au = c_AT[i * 4 + u];
#pragma unroll
      for (int v = 0; v < 4; ++v)
#pragma unroll
        for (int q = 0; q < 4; ++q) Y[u][v][q] += au * R[v][q];
    }
  }

  float* ob = out + ((size_t)((n0 + nl) * 64 + k) * 128 + ty * 4) * 128 + tx * 4;
#pragma unroll
  for (int u = 0; u < 4; ++u) {
    *(float4*)(ob + (size_t)u * 128)      = make_float4(Y[u][0][0], Y[u][1][0], Y[u][2][0], Y[u][3][0]);
    *(float4*)(ob + (size_t)u * 128 + 4)  = make_float4(Y[u][0][1], Y[u][1][1], Y[u][2][1], Y[u][3][1]);
    *(float4*)(ob + (size_t)u * 128 + 8)  = make_float4(Y[u][0][2], Y[u][1][2], Y[u][2][2], Y[u][3][2]);
    *(float4*)(ob + (size_t)u * 128 + 12) = make_float4(Y[u][0][3], Y[u][1][3], Y[u][2][3], Y[u][3][3]);
  }
}

extern "C" void kernel_launch(void* const* d_in, const int* in_sizes, int n_in,
                              void* d_out, int out_size, void* d_ws, size_t ws_size,
                              hipStream_t stream) {
  const float* x = (const float*)d_in[0];
  const float* w = (const float*)d_in[1];
  float* out = (float*)d_out;
  uint32_t* U = (uint32_t*)d_ws;
  const size_t U_bytes = 36ull * 64 * 64 * 4;        // 589824 (packed hi/lo)
  const size_t per_n = 2ull * 36 * 1024 * 64 * 4;    // V (uint) + M (float) per image
  size_t avail = ws_size > U_bytes ? ws_size - U_bytes : 0;
  int chunk = (int)(avail / per_n);
  if (chunk < 1) return;
  if (chunk > 8) chunk = 8;

  k_filter<<<16, 256, 0, stream>>>(w, U);
  for (int n0 = 0; n0 < 16; n0 += chunk) {
    int cn = (16 - n0) < chunk ? (16 - n0) : chunk;
    int Pchunk = cn * 1024;
    uint32_t* V = (uint32_t*)((char*)d_ws + U_bytes);
    float* M = (float*)(V + (size_t)36 * Pchunk * 64);
    int nPB = Pchunk / 128;
    k_input<<<cn*64,  256, 0, stream>>>(x, V, n0, Pchunk);
    k_gemm <<<36*nPB, 256, 0, stream>>>(V, U, M, Pchunk, nPB);
    k_out2 <<<64*cn,  256, 0, stream>>>(M, out, n0, Pchunk, cn);
  }
}

// Round 5
// 293.947 us; speedup vs baseline: 1.4621x; 1.4621x over previous
//
#include <hip/hip_runtime.h>
#include <hip/hip_fp16.h>

// Winograd F(4x4,3x3), fp32 in/out. x:[16,64,130,130] w:[64,64,3,3] -> y:[16,64,128,128]
// Pipeline: k_filter (U fp16 hi/lo, [ab][k][c]) -> k_input (V fp16 hi/lo, [ab][cg][p][4c]) ->
//           k_gemm (3-product f16 MFMA, M fp32 [ab][k][p]) -> k_out2 (A^T M A).
// half2 packing: each uint32 = (hi half in bits 0..15, lo half in bits 16..31) for one c.
// V layout [ab][cg16][p][c4]: thread (p,c4) stores at flat offset == tid -> fully coalesced.

typedef _Float16 half8_t __attribute__((ext_vector_type(8)));
typedef float floatx16 __attribute__((ext_vector_type(16)));

__constant__ float c_AT[24] = {   // c_AT[i*4+u] = A_T[u][i]
  1.f, 0.f, 0.f, 0.f,
  1.f, 1.f, 1.f, 1.f,
  1.f,-1.f, 1.f,-1.f,
  1.f, 2.f, 4.f, 8.f,
  1.f,-2.f, 4.f,-8.f,
  0.f, 0.f, 0.f, 1.f
};

__device__ __forceinline__ uint32_t pack_hilo(float v) {
  __half hh = __float2half(v);
  float r = v - __half2float(hh);
  __half hl = __float2half(r);
  return (uint32_t)__half_as_ushort(hh) | ((uint32_t)__half_as_ushort(hl) << 16);
}
__device__ __forceinline__ uint32_t phi(uint32_t w0, uint32_t w1) {
  return __builtin_amdgcn_perm(w1, w0, 0x05040100u);   // hi halves of (c, c+1)
}
__device__ __forceinline__ uint32_t plo(uint32_t w0, uint32_t w1) {
  return __builtin_amdgcn_perm(w1, w0, 0x07060302u);   // lo halves of (c, c+1)
}
union H8 { uint32_t u[4]; half8_t h; };

// ---------------- K0: filter transform U = G w G^T -> packed hi/lo, [ab][k][c] ----------------
__global__ __launch_bounds__(256) void k_filter(const float* __restrict__ w,
                                                uint32_t* __restrict__ U) {
  int g = blockIdx.x * 256 + threadIdx.x;     // 0..4095
  int c = g & 63;                              // lane-fast -> coalesced U stores
  int k = g >> 6;
  const float* wp = w + (size_t)(k * 64 + c) * 9;
  float w00 = wp[0], w01 = wp[1], w02 = wp[2];
  float w10 = wp[3], w11 = wp[4], w12 = wp[5];
  float w20 = wp[6], w21 = wp[7], w22 = wp[8];
  const float G[6][3] = {
    {0.25f, 0.f, 0.f},
    {-1.f/6.f, -1.f/6.f, -1.f/6.f},
    {-1.f/6.f,  1.f/6.f, -1.f/6.f},
    {1.f/24.f,  1.f/12.f, 1.f/6.f},
    {1.f/24.f, -1.f/12.f, 1.f/6.f},
    {0.f, 0.f, 1.f}
  };
  float t[6][3];
#pragma unroll
  for (int a = 0; a < 6; ++a) {
    t[a][0] = G[a][0]*w00 + G[a][1]*w10 + G[a][2]*w20;
    t[a][1] = G[a][0]*w01 + G[a][1]*w11 + G[a][2]*w21;
    t[a][2] = G[a][0]*w02 + G[a][1]*w12 + G[a][2]*w22;
  }
#pragma unroll
  for (int a = 0; a < 6; ++a) {
#pragma unroll
    for (int b = 0; b < 6; ++b) {
      float u = G[b][0]*t[a][0] + G[b][1]*t[a][1] + G[b][2]*t[a][2];
      U[((size_t)(a*6+b)*64 + k)*64 + c] = pack_hilo(u);
    }
  }
}

// ---------------- K1: input transform -> V[ab][cg][p][4c] packed hi/lo ----------------
// block = (nl, ty2: 2 tile-rows = 64 p, cgq: 16 c). 4 chunks of 4 c. grid = cn*64.
// Direct coalesced global stores (thread (p,c4) -> flat offset tid), no LDS output buffer.
__global__ __launch_bounds__(256) void k_input(const float* __restrict__ x,
                                               uint32_t* __restrict__ V,
                                               int n0, int Pchunk) {
  __shared__ float XL[4*1333];          // [4c][10 rows x 133]; plane stride odd -> banks mix
  const int tid = threadIdx.x;
  const int bi  = blockIdx.x;
  const int cgq = bi & 3;
  const int ty2 = (bi >> 2) & 15;
  const int nl  = bi >> 6;
  const int h0  = ty2 * 8;              // x rows h0..h0+9

  const int c4 = tid & 3;
  const int p  = tid >> 2;              // 0..63
  const int trow = p >> 5, pl = p & 31;
  const size_t pglob = (size_t)nl*1024 + ty2*64 + p;

  for (int ch = 0; ch < 4; ++ch) {
    const int cg = cgq*4 + ch;
    const int cbase = cg*4;
    __syncthreads();                    // protect XL reuse from previous chunk's readers
    // stage x[4c][10r][130] (float2 global loads)
    for (int idx = tid; idx < 4*10*65; idx += 256) {
      int cc = idx / 650; int rem = idx - cc*650; int r = rem/65; int j = rem - r*65;
      const float* xr = x + ((size_t)((n0+nl)*64 + cbase + cc)*130 + h0 + r)*130;
      float2 v = *(const float2*)(xr + j*2);
      XL[cc*1333 + r*133 + j*2]     = v.x;
      XL[cc*1333 + r*133 + j*2 + 1] = v.y;
    }
    __syncthreads();
    // transform one (p, c4) per thread
    const float* bl = &XL[c4*1333 + (trow*4)*133 + pl*4];
    float t1[6][6];
#pragma unroll
    for (int j = 0; j < 6; ++j) {
      float d0 = bl[0*133+j], d1 = bl[1*133+j], d2 = bl[2*133+j];
      float d3 = bl[3*133+j], d4 = bl[4*133+j], d5 = bl[5*133+j];
      t1[0][j] =  4.f*d0 - 5.f*d2 + d4;
      t1[1][j] = -4.f*d1 - 4.f*d2 + d3 + d4;
      t1[2][j] =  4.f*d1 - 4.f*d2 - d3 + d4;
      t1[3][j] = -2.f*d1 -     d2 + 2.f*d3 + d4;
      t1[4][j] =  2.f*d1 -     d2 - 2.f*d3 + d4;
      t1[5][j] =  4.f*d1 - 5.f*d3 + d5;
    }
#pragma unroll
    for (int a = 0; a < 6; ++a) {
      float s0=t1[a][0], s1=t1[a][1], s2=t1[a][2], s3=t1[a][3], s4=t1[a][4], s5=t1[a][5];
      float v0 =  4.f*s0 - 5.f*s2 + s4;
      float v1 = -4.f*s1 - 4.f*s2 + s3 + s4;
      float v2 =  4.f*s1 - 4.f*s2 - s3 + s4;
      float v3 = -2.f*s1 -     s2 + 2.f*s3 + s4;
      float v4 =  2.f*s1 -     s2 - 2.f*s3 + s4;
      float v5 =  4.f*s1 - 5.f*s3 + s5;
      // V flat uint index: ((ab*16 + cg)*Pchunk + p)*4 + c4  -> coalesced (== lane order)
      uint32_t* vb = V + ((size_t)(a*6)*16 + cg) * Pchunk * 4 + pglob*4 + c4;
      const size_t abstep = (size_t)16 * Pchunk * 4;
      vb[0*abstep] = pack_hilo(v0);
      vb[1*abstep] = pack_hilo(v1);
      vb[2*abstep] = pack_hilo(v2);
      vb[3*abstep] = pack_hilo(v3);
      vb[4*abstep] = pack_hilo(v4);
      vb[5*abstep] = pack_hilo(v5);
    }
  }
}

// ---------------- K2: 3-product f16 MFMA GEMM: M[ab][k][p] = sum_c U*V ----------------
// block = one ab x 128 p x 64 k; Vs = [128p][16 units of 16B], unit xor-swizzled by p&15.
__global__ __launch_bounds__(256) void k_gemm(const uint32_t* __restrict__ V,
                                              const uint32_t* __restrict__ U,
                                              float* __restrict__ M,
                                              int Pchunk, int nPB) {
  __shared__ uint32_t Vs[128*64];       // 32 KB
  const int tid  = threadIdx.x;
  const int lane = tid & 63;
  const int wv   = tid >> 6;
  const unsigned bx = blockIdx.x;
  const int ab = bx / (unsigned)nPB;
  const int pb = bx - ab * nPB;
  const int p0 = pb * 128;

  // ---- stage V tile: 16 cg-slabs x 128 p, each (cg,p) one uint4
  const uint4* Vg4 = (const uint4*)V;
  uint4 tmp[8];
#pragma unroll
  for (int i = 0; i < 8; ++i) {
    int f = tid + i*256; int cg = f >> 7; int pp = f & 127;
    tmp[i] = Vg4[((size_t)ab*16 + cg)*Pchunk + p0 + pp];
  }
#pragma unroll
  for (int i = 0; i < 8; ++i) {
    int f = tid + i*256; int cg = f >> 7; int pp = f & 127;
    *(uint4*)&Vs[pp*64 + (cg ^ (pp & 15))*4] = tmp[i];
  }
  __syncthreads();

  // ---- preload U A-frags: wave covers 64 k (2 ktiles); A[m=lane&31][k-half=lane>>5]
  const int kg = lane >> 5;
  const int m  = lane & 31;
  half8_t Uhi[2][4], Ulo[2][4];
#pragma unroll
  for (int t = 0; t < 2; ++t) {
    int k = t*32 + m;
    const uint32_t* ub = U + ((size_t)ab*64 + k)*64;
#pragma unroll
    for (int cc = 0; cc < 4; ++cc) {
      uint4 qa = *(const uint4*)(ub + cc*16 + kg*8);
      uint4 qb = *(const uint4*)(ub + cc*16 + kg*8 + 4);
      H8 hi, lo;
      hi.u[0] = phi(qa.x, qa.y); hi.u[1] = phi(qa.z, qa.w);
      hi.u[2] = phi(qb.x, qb.y); hi.u[3] = phi(qb.z, qb.w);
      lo.u[0] = plo(qa.x, qa.y); lo.u[1] = plo(qa.z, qa.w);
      lo.u[2] = plo(qb.x, qb.y); lo.u[3] = plo(qb.z, qb.w);
      Uhi[t][cc] = hi.h; Ulo[t][cc] = lo.h;
    }
  }

  floatx16 acc[2];
#pragma unroll
  for (int t = 0; t < 2; ++t)
#pragma unroll
    for (int r = 0; r < 16; ++r) acc[t][r] = 0.f;

  const int plane = wv*32 + m;          // this wave's p for B-frags
#pragma unroll
  for (int cc = 0; cc < 4; ++cc) {
    int u0 = (cc*4 + kg*2) ^ (plane & 15);
    int u1 = (cc*4 + kg*2 + 1) ^ (plane & 15);
    uint4 qa = *(const uint4*)&Vs[plane*64 + u0*4];
    uint4 qb = *(const uint4*)&Vs[plane*64 + u1*4];
    H8 vhi, vlo;
    vhi.u[0] = phi(qa.x, qa.y); vhi.u[1] = phi(qa.z, qa.w);
    vhi.u[2] = phi(qb.x, qb.y); vhi.u[3] = phi(qb.z, qb.w);
    vlo.u[0] = plo(qa.x, qa.y); vlo.u[1] = plo(qa.z, qa.w);
    vlo.u[2] = plo(qb.x, qb.y); vlo.u[3] = plo(qb.z, qb.w);
#pragma unroll
    for (int t = 0; t < 2; ++t) {
      acc[t] = __builtin_amdgcn_mfma_f32_32x32x16_f16(Uhi[t][cc], vhi.h, acc[t], 0, 0, 0);
      acc[t] = __builtin_amdgcn_mfma_f32_32x32x16_f16(Uhi[t][cc], vlo.h, acc[t], 0, 0, 0);
      acc[t] = __builtin_amdgcn_mfma_f32_32x32x16_f16(Ulo[t][cc], vhi.h, acc[t], 0, 0, 0);
    }
  }

  // ---- store M[ab][k][p]: col(p)=lane&31, row(k)=(r&3)+8*(r>>2)+4*(lane>>5)
  const int pout = p0 + wv*32 + m;
#pragma unroll
  for (int t = 0; t < 2; ++t) {
#pragma unroll
    for (int r = 0; r < 16; ++r) {
      int k = t*32 + (r & 3) + 8*(r >> 2) + 4*kg;
      M[((size_t)ab*64 + k)*Pchunk + pout] = acc[t][r];
    }
  }
}

// ---------------- K3: output transform Y = A_T M A, 4 p per thread ----------------
__global__ __launch_bounds__(256) void k_out2(const float* __restrict__ M,
                                              float* __restrict__ out,
                                              int n0, int Pchunk, int bpk) {
  const unsigned bx = blockIdx.x;
  const int k    = bx / (unsigned)bpk;
  const int pblk = bx - k * bpk;
  const int p    = pblk * 1024 + threadIdx.x * 4;
  const int nl = p >> 10;
  const int ty = (p >> 5) & 31;
  const int tx = p & 31;

  const float* mp = M + (size_t)k * Pchunk + p;
  const size_t abstride = (size_t)64 * Pchunk;

  float Y[4][4][4];   // [u][v][pvec]
#pragma unroll
  for (int u = 0; u < 4; ++u)
#pragma unroll
    for (int v = 0; v < 4; ++v)
#pragma unroll
      for (int q = 0; q < 4; ++q) Y[u][v][q] = 0.f;

#pragma unroll
  for (int i = 0; i < 6; ++i) {
    float R[4][4];
#pragma unroll
    for (int v = 0; v < 4; ++v)
#pragma unroll
      for (int q = 0; q < 4; ++q) R[v][q] = 0.f;
#pragma unroll
    for (int j = 0; j < 6; ++j) {
      float4 m4 = *(const float4*)(mp + (size_t)(i * 6 + j) * abstride);
      float mm[4] = {m4.x, m4.y, m4.z, m4.w};
#pragma unroll
      for (int v = 0; v < 4; ++v) {
        float av = c_AT[j * 4 + v];
#pragma unroll
        for (int q = 0; q < 4; ++q) R[v][q] += av * mm[q];
      }
    }
#pragma unroll
    for (int u = 0; u < 4; ++u) {
      float au = c_AT[i * 4 + u];
#pragma unroll
      for (int v = 0; v < 4; ++v)
#pragma unroll
        for (int q = 0; q < 4; ++q) Y[u][v][q] += au * R[v][q];
    }
  }

  float* ob = out + ((size_t)((n0 + nl) * 64 + k) * 128 + ty * 4) * 128 + tx * 4;
#pragma unroll
  for (int u = 0; u < 4; ++u) {
    *(float4*)(ob + (size_t)u * 128)      = make_float4(Y[u][0][0], Y[u][1][0], Y[u][2][0], Y[u][3][0]);
    *(float4*)(ob + (size_t)u * 128 + 4)  = make_float4(Y[u][0][1], Y[u][1][1], Y[u][2][1], Y[u][3][1]);
    *(float4*)(ob + (size_t)u * 128 + 8)  = make_float4(Y[u][0][2], Y[u][1][2], Y[u][2][2], Y[u][3][2]);
    *(float4*)(ob + (size_t)u * 128 + 12) = make_float4(Y[u][0][3], Y[u][1][3], Y[u][2][3], Y[u][3][3]);
  }
}

extern "C" void kernel_launch(void* const* d_in, const int* in_sizes, int n_in,
                              void* d_out, int out_size, void* d_ws, size_t ws_size,
                              hipStream_t stream) {
  const float* x = (const float*)d_in[0];
  const float* w = (const float*)d_in[1];
  float* out = (float*)d_out;
  uint32_t* U = (uint32_t*)d_ws;
  const size_t U_bytes = 36ull * 64 * 64 * 4;        // 589824 (packed hi/lo)
  const size_t per_n = 2ull * 36 * 1024 * 64 * 4;    // V (uint) + M (float) per image
  size_t avail = ws_size > U_bytes ? ws_size - U_bytes : 0;
  int chunk = (int)(avail / per_n);
  if (chunk < 1) return;
  if (chunk > 8) chunk = 8;                          // keep V+M inside 256 MB L3

  k_filter<<<16, 256, 0, stream>>>(w, U);
  for (int n0 = 0; n0 < 16; n0 += chunk) {
    int cn = (16 - n0) < chunk ? (16 - n0) : chunk;
    int Pchunk = cn * 1024;
    uint32_t* V = (uint32_t*)((char*)d_ws + U_bytes);
    float* M = (float*)(V + (size_t)36 * Pchunk * 64);
    int nPB = Pchunk / 128;
    k_input<<<cn*64,  256, 0, stream>>>(x, V, n0, Pchunk);
    k_gemm <<<36*nPB, 256, 0, stream>>>(V, U, M, Pchunk, nPB);
    k_out2 <<<64*cn,  256, 0, stream>>>(M, out, n0, Pchunk, cn);
  }
}